// Round 1
// baseline (665.845 us; speedup 1.0000x reference)
//
#include <hip/hip_runtime.h>
#include <hip/hip_bf16.h>

#define B_ 2
#define H_ 16
#define S_ 2048
#define D_ 32
#define DM_ 512

typedef __attribute__((ext_vector_type(8))) short short8;
typedef __attribute__((ext_vector_type(4))) float f32x4;

__device__ __forceinline__ unsigned short f2bf(float f) {
    unsigned int u = __builtin_bit_cast(unsigned int, f);
    unsigned int r = (u + 0x7fffu + ((u >> 16) & 1u)) >> 16;
    return (unsigned short)r;
}
__device__ __forceinline__ float bf2f(unsigned short s) {
    unsigned int u = ((unsigned int)s) << 16;
    return __builtin_bit_cast(float, u);
}

// ---------------------------------------------------------------------------
// Shared 64x64 NT GEMM tile: Y[row][col] = sum_d X[row][d] * W[col][d]
// X: [M][512] fp32 row-major, W: [512][512] fp32 row-major (dot over rows)
// 256 threads = 4 waves, each wave a 32x32 sub-tile via 2x2 mfma 16x16x32 bf16
// ---------------------------------------------------------------------------
__device__ __forceinline__ void gemm64_tile(const float* __restrict__ X,
                                            const float* __restrict__ W,
                                            int row0, int col0,
                                            unsigned short* ldsA,
                                            unsigned short* ldsB,
                                            f32x4 acc[2][2]) {
    const int tid = threadIdx.x;
    const int w = tid >> 6, l = tid & 63, lr = l & 15, lg = l >> 4;
    const int wr = w >> 1, wc = w & 1;
    const int sr = tid >> 2, seg = tid & 3;

    for (int kt = 0; kt < 16; ++kt) {
        int k0 = kt * 32;
        __syncthreads();
        // stage A (X rows) and B (W rows) as bf16, rows padded to 40 shorts
        {
            const float* ap = X + (size_t)(row0 + sr) * DM_ + k0 + seg * 8;
            float4 a0 = *(const float4*)ap;
            float4 a1 = *(const float4*)(ap + 4);
            short8 av;
            av[0] = (short)f2bf(a0.x); av[1] = (short)f2bf(a0.y);
            av[2] = (short)f2bf(a0.z); av[3] = (short)f2bf(a0.w);
            av[4] = (short)f2bf(a1.x); av[5] = (short)f2bf(a1.y);
            av[6] = (short)f2bf(a1.z); av[7] = (short)f2bf(a1.w);
            *(short8*)(ldsA + sr * 40 + seg * 8) = av;

            const float* bp = W + (size_t)(col0 + sr) * DM_ + k0 + seg * 8;
            float4 b0 = *(const float4*)bp;
            float4 b1 = *(const float4*)(bp + 4);
            short8 bv;
            bv[0] = (short)f2bf(b0.x); bv[1] = (short)f2bf(b0.y);
            bv[2] = (short)f2bf(b0.z); bv[3] = (short)f2bf(b0.w);
            bv[4] = (short)f2bf(b1.x); bv[5] = (short)f2bf(b1.y);
            bv[6] = (short)f2bf(b1.z); bv[7] = (short)f2bf(b1.w);
            *(short8*)(ldsB + sr * 40 + seg * 8) = bv;
        }
        __syncthreads();
        short8 af0 = *(short8*)(ldsA + (32 * wr + lr) * 40 + lg * 8);
        short8 af1 = *(short8*)(ldsA + (32 * wr + 16 + lr) * 40 + lg * 8);
        short8 bf0 = *(short8*)(ldsB + (32 * wc + lr) * 40 + lg * 8);
        short8 bf1 = *(short8*)(ldsB + (32 * wc + 16 + lr) * 40 + lg * 8);
        acc[0][0] = __builtin_amdgcn_mfma_f32_16x16x32_bf16(af0, bf0, acc[0][0], 0, 0, 0);
        acc[0][1] = __builtin_amdgcn_mfma_f32_16x16x32_bf16(af0, bf1, acc[0][1], 0, 0, 0);
        acc[1][0] = __builtin_amdgcn_mfma_f32_16x16x32_bf16(af1, bf0, acc[1][0], 0, 0, 0);
        acc[1][1] = __builtin_amdgcn_mfma_f32_16x16x32_bf16(af1, bf1, acc[1][1], 0, 0, 0);
    }
}

// ---------------------------------------------------------------------------
// K1: projections. mode: 0=q (writes qu=q+u_bias, qv=q+v_bias), 1=k, 2=v (transposed), 3=pe
// ---------------------------------------------------------------------------
__global__ __launch_bounds__(256) void proj_kernel(
    const float* __restrict__ q_in, const float* __restrict__ k_in,
    const float* __restrict__ v_in, const float* __restrict__ p_in,
    const float* __restrict__ Wq, const float* __restrict__ Wk,
    const float* __restrict__ Wv, const float* __restrict__ Wp,
    const float* __restrict__ bq, const float* __restrict__ bk,
    const float* __restrict__ bv,
    const float* __restrict__ ub, const float* __restrict__ vb,
    unsigned short* __restrict__ quB, unsigned short* __restrict__ qvB,
    unsigned short* __restrict__ kB, unsigned short* __restrict__ peB,
    unsigned short* __restrict__ vtB) {
    __shared__ unsigned short ldsA[64 * 40];
    __shared__ unsigned short ldsB[64 * 40];

    const int mode = blockIdx.z;
    const float* X = (mode == 0) ? q_in : (mode == 1) ? k_in : (mode == 2) ? v_in : p_in;
    const float* W = (mode == 0) ? Wq : (mode == 1) ? Wk : (mode == 2) ? Wv : Wp;
    const float* bias = (mode == 0) ? bq : (mode == 1) ? bk : (mode == 2) ? bv : nullptr;

    const int row0 = blockIdx.x * 64, col0 = blockIdx.y * 64;
    f32x4 acc[2][2];
    for (int i = 0; i < 2; ++i)
        for (int j = 0; j < 2; ++j)
            acc[i][j] = (f32x4){0.f, 0.f, 0.f, 0.f};

    gemm64_tile(X, W, row0, col0, ldsA, ldsB, acc);

    const int tid = threadIdx.x;
    const int w = tid >> 6, l = tid & 63, lr = l & 15, lg = l >> 4;
    const int wr = w >> 1, wc = w & 1;

    for (int i = 0; i < 2; ++i) {
        for (int j = 0; j < 2; ++j) {
            int colg = col0 + 32 * wc + 16 * j + lr;
            int h = colg >> 5, d = colg & 31;
            float bb = bias ? bias[colg] : 0.f;
            int rbase = row0 + 32 * wr + 16 * i + 4 * lg;
            if (mode == 2) {
                int b = rbase >> 11;
                int s0 = rbase & 2047;
                ushort4 pk;
                pk.x = f2bf(acc[i][j][0] + bb);
                pk.y = f2bf(acc[i][j][1] + bb);
                pk.z = f2bf(acc[i][j][2] + bb);
                pk.w = f2bf(acc[i][j][3] + bb);
                size_t o = ((size_t)((b * H_ + h) * D_ + d)) * S_ + s0;
                *(ushort4*)(vtB + o) = pk;
            } else {
                float ubv = 0.f, vbv = 0.f;
                if (mode == 0) { ubv = ub[colg]; vbv = vb[colg]; }
                for (int e = 0; e < 4; ++e) {
                    int rg = rbase + e;
                    int b = rg >> 11, s = rg & 2047;
                    size_t o = ((size_t)((b * H_ + h) * S_ + s)) * D_ + d;
                    float y = acc[i][j][e] + bb;
                    if (mode == 0) {
                        quB[o] = f2bf(y + ubv);
                        qvB[o] = f2bf(y + vbv);
                    } else if (mode == 1) {
                        kB[o] = f2bf(y);
                    } else {
                        peB[o] = f2bf(y);
                    }
                }
            }
        }
    }
}

// ---------------------------------------------------------------------------
// K2: fused content+pos scores, softmax, attn write (fp32), PV -> ctx
// grid (S/16, H, B), 512 threads = 8 waves
// ---------------------------------------------------------------------------
__global__ __launch_bounds__(512) void attn_kernel(
    const unsigned short* __restrict__ quB, const unsigned short* __restrict__ qvB,
    const unsigned short* __restrict__ kB, const unsigned short* __restrict__ peB,
    const unsigned short* __restrict__ vtB, const unsigned char* __restrict__ mask,
    float* __restrict__ attn_out, float* __restrict__ ctx) {
    __shared__ unsigned short sc[16 * 2064];   // bf16 scores, row stride 2064
    __shared__ unsigned short kt[256 * 40];    // staged k/pe rows, stride 40
    __shared__ float red[8 * 16 * 32];         // PV wave partials
    __shared__ float rowm[16], rowl[16];

    const int tid = threadIdx.x, w = tid >> 6, l = tid & 63, lr = l & 15, lg = l >> 4;
    const int q0 = blockIdx.x * 16, h = blockIdx.y, b = blockIdx.z;
    const size_t headoff = ((size_t)(b * H_ + h)) * S_ * D_;
    const float SCALE = 0.044194173824159216f;
    const int srow = tid >> 1, shalf = tid & 1;

    // A-fragments (held for the whole kernel)
    short8 qu_f = *(const short8*)(quB + headoff + (size_t)(q0 + lr) * D_ + lg * 8);
    short8 qvA_f = *(const short8*)(qvB + headoff + (size_t)(q0 + lr) * D_ + lg * 8);
    int rB = q0 + 1 + lr; if (rB > S_ - 1) rB = S_ - 1;
    short8 qvB_f = *(const short8*)(qvB + headoff + (size_t)rB * D_ + lg * 8);

    // ---- content pass: sc[r][k'] = bf16(qk*SCALE + maskterm) ----
    for (int t = 0; t < 8; ++t) {
        __syncthreads();
        {
            const unsigned short* src = kB + headoff + (size_t)(256 * t + srow) * D_ + shalf * 16;
            *(short8*)(kt + srow * 40 + shalf * 16) = *(const short8*)src;
            *(short8*)(kt + srow * 40 + shalf * 16 + 8) = *(const short8*)(src + 8);
        }
        __syncthreads();
        for (int st = 0; st < 2; ++st) {
            int cb = 32 * w + 16 * st;
            short8 bfr = *(short8*)(kt + (cb + lr) * 40 + lg * 8);
            f32x4 dd = (f32x4){0.f, 0.f, 0.f, 0.f};
            dd = __builtin_amdgcn_mfma_f32_16x16x32_bf16(qu_f, bfr, dd, 0, 0, 0);
            int kcol = 256 * t + cb + lr;
            float mk = mask[b * S_ + kcol] ? -1e9f : 0.f;
            for (int i = 0; i < 4; ++i) {
                int r = 4 * lg + i;
                sc[r * 2064 + kcol] = f2bf(dd[i] * SCALE + mk);
            }
        }
    }

    // ---- pos pass A: delta = k'-q in [-q, 0]; P[q][S-1+delta] ----
    {
        int nA = (q0 + 16 + 255) >> 8;
        int base_pa = S_ - 16 - q0;
        for (int tu = 0; tu < nA; ++tu) {
            __syncthreads();
            {
                int pr = base_pa + 256 * tu + srow;
                if (pr > S_ - 1) pr = S_ - 1;
                const unsigned short* src = peB + headoff + (size_t)pr * D_ + shalf * 16;
                *(short8*)(kt + srow * 40 + shalf * 16) = *(const short8*)src;
                *(short8*)(kt + srow * 40 + shalf * 16 + 8) = *(const short8*)(src + 8);
            }
            __syncthreads();
            for (int st = 0; st < 2; ++st) {
                int cb = 32 * w + 16 * st;
                short8 bfr = *(short8*)(kt + (cb + lr) * 40 + lg * 8);
                f32x4 dd = (f32x4){0.f, 0.f, 0.f, 0.f};
                dd = __builtin_amdgcn_mfma_f32_16x16x32_bf16(qvA_f, bfr, dd, 0, 0, 0);
                int u = 256 * tu + cb + lr;
                int delta = u - (q0 + 15);
                for (int i = 0; i < 4; ++i) {
                    int r = 4 * lg + i;
                    int q = q0 + r;
                    if (delta <= 0 && delta >= -q) {
                        int a = r * 2064 + q + delta;
                        sc[a] = f2bf(bf2f(sc[a]) + dd[i] * SCALE);
                    }
                }
            }
        }
    }

    // ---- pos pass B: delta = k'-q in [2, S-1-q]; P[q+1][delta-2] ----
    {
        int nB = (S_ - q0 + 255) >> 8;
        for (int tu = 0; tu < nB; ++tu) {
            __syncthreads();
            {
                int pr = 256 * tu + srow - 2;
                if (pr < 0) pr = 0;
                if (pr > S_ - 1) pr = S_ - 1;
                const unsigned short* src = peB + headoff + (size_t)pr * D_ + shalf * 16;
                *(short8*)(kt + srow * 40 + shalf * 16) = *(const short8*)src;
                *(short8*)(kt + srow * 40 + shalf * 16 + 8) = *(const short8*)(src + 8);
            }
            __syncthreads();
            for (int st = 0; st < 2; ++st) {
                int cb = 32 * w + 16 * st;
                short8 bfr = *(short8*)(kt + (cb + lr) * 40 + lg * 8);
                f32x4 dd = (f32x4){0.f, 0.f, 0.f, 0.f};
                dd = __builtin_amdgcn_mfma_f32_16x16x32_bf16(qvB_f, bfr, dd, 0, 0, 0);
                int delta = 256 * tu + cb + lr;
                for (int i = 0; i < 4; ++i) {
                    int r = 4 * lg + i;
                    int q = q0 + r;
                    if (delta >= 2 && delta <= S_ - 1 - q) {
                        int a = r * 2064 + q + delta;
                        sc[a] = f2bf(bf2f(sc[a]) + dd[i] * SCALE);
                    }
                }
            }
        }
    }

    __syncthreads();

    // ---- softmax reduce: row r handled by 32 lanes ----
    {
        int r = tid >> 5, c0 = (tid & 31) * 64;
        float m = -1e30f, lsum = 0.f;
        for (int j = 0; j < 64; ++j) {
            float v = bf2f(sc[r * 2064 + c0 + j]);
            if (v > m) { lsum = lsum * __expf(m - v) + 1.f; m = v; }
            else lsum += __expf(v - m);
        }
        for (int off = 1; off < 32; off <<= 1) {
            float mo = __shfl_xor(m, off);
            float lo = __shfl_xor(lsum, off);
            float nm = fmaxf(m, mo);
            lsum = lsum * __expf(m - nm) + lo * __expf(mo - nm);
            m = nm;
        }
        if ((tid & 31) == 0) { rowm[r] = m; rowl[r] = lsum; }
    }
    __syncthreads();

    // ---- attn write (fp32 to global) + bf16 attn back into sc for PV ----
    {
        float* abase = attn_out + ((size_t)((b * H_ + h) * S_ + q0)) * S_;
        int c = tid * 4;
        for (int r = 0; r < 16; ++r) {
            float m = rowm[r];
            float li = 1.0f / rowl[r];
            ushort4 s4 = *(ushort4*)(sc + r * 2064 + c);
            float4 av;
            av.x = __expf(bf2f(s4.x) - m) * li;
            av.y = __expf(bf2f(s4.y) - m) * li;
            av.z = __expf(bf2f(s4.z) - m) * li;
            av.w = __expf(bf2f(s4.w) - m) * li;
            *(float4*)(abase + (size_t)r * S_ + c) = av;
            ushort4 bb;
            bb.x = f2bf(av.x); bb.y = f2bf(av.y); bb.z = f2bf(av.z); bb.w = f2bf(av.w);
            *(ushort4*)(sc + r * 2064 + c) = bb;
        }
    }
    __syncthreads();

    // ---- PV: ctx[q][d] = sum_k attn[q][k] * V[k][d]; wave w covers K [256w,+256) ----
    {
        f32x4 a0 = (f32x4){0.f, 0.f, 0.f, 0.f};
        f32x4 a1 = (f32x4){0.f, 0.f, 0.f, 0.f};
        const unsigned short* vbase = vtB + ((size_t)(b * H_ + h)) * D_ * S_;
        for (int ks = 0; ks < 8; ++ks) {
            int koff = 256 * w + 32 * ks;
            short8 af = *(short8*)(sc + lr * 2064 + koff + lg * 8);
            short8 b0 = *(const short8*)(vbase + (size_t)lr * S_ + koff + lg * 8);
            short8 b1 = *(const short8*)(vbase + (size_t)(16 + lr) * S_ + koff + lg * 8);
            a0 = __builtin_amdgcn_mfma_f32_16x16x32_bf16(af, b0, a0, 0, 0, 0);
            a1 = __builtin_amdgcn_mfma_f32_16x16x32_bf16(af, b1, a1, 0, 0, 0);
        }
        for (int i = 0; i < 4; ++i) {
            red[(w * 16 + 4 * lg + i) * 32 + lr] = a0[i];
            red[(w * 16 + 4 * lg + i) * 32 + 16 + lr] = a1[i];
        }
    }
    __syncthreads();
    {
        int r = tid >> 5, d = tid & 31;
        float s = 0.f;
        for (int ww = 0; ww < 8; ++ww) s += red[(ww * 16 + r) * 32 + d];
        ctx[((size_t)(b * S_ + q0 + r)) * DM_ + h * D_ + d] = s;
    }
}

// ---------------------------------------------------------------------------
// K3: out = ctx @ Wo^T + bo
// ---------------------------------------------------------------------------
__global__ __launch_bounds__(256) void outproj_kernel(
    const float* __restrict__ ctx, const float* __restrict__ Wo,
    const float* __restrict__ bo, float* __restrict__ outp) {
    __shared__ unsigned short ldsA[64 * 40];
    __shared__ unsigned short ldsB[64 * 40];
    const int row0 = blockIdx.x * 64, col0 = blockIdx.y * 64;
    f32x4 acc[2][2];
    for (int i = 0; i < 2; ++i)
        for (int j = 0; j < 2; ++j)
            acc[i][j] = (f32x4){0.f, 0.f, 0.f, 0.f};
    gemm64_tile(ctx, Wo, row0, col0, ldsA, ldsB, acc);
    const int tid = threadIdx.x;
    const int w = tid >> 6, l = tid & 63, lr = l & 15, lg = l >> 4;
    const int wr = w >> 1, wc = w & 1;
    for (int i = 0; i < 2; ++i) {
        for (int j = 0; j < 2; ++j) {
            int colg = col0 + 32 * wc + 16 * j + lr;
            float bb = bo[colg];
            int rbase = row0 + 32 * wr + 16 * i + 4 * lg;
            for (int e = 0; e < 4; ++e) {
                outp[(size_t)(rbase + e) * DM_ + colg] = acc[i][j][e] + bb;
            }
        }
    }
}

extern "C" void kernel_launch(void* const* d_in, const int* in_sizes, int n_in,
                              void* d_out, int out_size, void* d_ws, size_t ws_size,
                              hipStream_t stream) {
    const float* q_in = (const float*)d_in[0];
    const float* k_in = (const float*)d_in[1];
    const float* v_in = (const float*)d_in[2];
    const float* p_in = (const float*)d_in[3];
    const unsigned char* mask = (const unsigned char*)d_in[4];
    const float* Wq = (const float*)d_in[5];
    const float* bq = (const float*)d_in[6];
    const float* Wk = (const float*)d_in[7];
    const float* bk = (const float*)d_in[8];
    const float* Wv = (const float*)d_in[9];
    const float* bv = (const float*)d_in[10];
    const float* Wp = (const float*)d_in[11];
    const float* ub = (const float*)d_in[12];
    const float* vb = (const float*)d_in[13];
    const float* Wo = (const float*)d_in[14];
    const float* bo = (const float*)d_in[15];

    char* ws = (char*)d_ws;
    const size_t BUF = 1u << 22;  // 4 MB per bf16 [B,H,S,D] buffer
    unsigned short* quB = (unsigned short*)(ws);
    unsigned short* qvB = (unsigned short*)(ws + BUF);
    unsigned short* kB  = (unsigned short*)(ws + 2 * BUF);
    unsigned short* peB = (unsigned short*)(ws + 3 * BUF);
    unsigned short* vtB = (unsigned short*)(ws + 4 * BUF);
    float* ctx = (float*)(ws + 5 * BUF);  // [B*S][512] fp32, 8 MB

    float* outp = (float*)d_out;
    float* attn = outp + (size_t)B_ * S_ * DM_;

    hipLaunchKernelGGL(proj_kernel, dim3(64, 8, 4), dim3(256), 0, stream,
                       q_in, k_in, v_in, p_in, Wq, Wk, Wv, Wp, bq, bk, bv,
                       ub, vb, quB, qvB, kB, peB, vtB);
    hipLaunchKernelGGL(attn_kernel, dim3(S_ / 16, H_, B_), dim3(512), 0, stream,
                       quB, qvB, kB, peB, vtB, mask, attn, ctx);
    hipLaunchKernelGGL(outproj_kernel, dim3(64, 8, 1), dim3(256), 0, stream,
                       ctx, Wo, bo, outp);
}

// Round 2
// 321.129 us; speedup vs baseline: 2.0735x; 2.0735x over previous
//
#include <hip/hip_runtime.h>
#include <hip/hip_bf16.h>

#define B_ 2
#define H_ 16
#define S_ 2048
#define D_ 32
#define DM_ 512
#define SCW 2052  // sc row stride in shorts: 4-row stride = 4104 dwords ≡ 8 mod 32 banks

typedef __attribute__((ext_vector_type(8))) short short8;
typedef __attribute__((ext_vector_type(4))) float f32x4;

__device__ __forceinline__ unsigned short f2bf(float f) {
    unsigned int u = __builtin_bit_cast(unsigned int, f);
    unsigned int r = (u + 0x7fffu + ((u >> 16) & 1u)) >> 16;
    return (unsigned short)r;
}
__device__ __forceinline__ float bf2f(unsigned short s) {
    unsigned int u = ((unsigned int)s) << 16;
    return __builtin_bit_cast(float, u);
}

// ---------------------------------------------------------------------------
// Shared 64x64 NT GEMM tile: Y[row][col] = sum_d X[row][d] * W[col][d]
// ---------------------------------------------------------------------------
__device__ __forceinline__ void gemm64_tile(const float* __restrict__ X,
                                            const float* __restrict__ W,
                                            int row0, int col0,
                                            unsigned short* ldsA,
                                            unsigned short* ldsB,
                                            f32x4 acc[2][2]) {
    const int tid = threadIdx.x;
    const int w = tid >> 6, l = tid & 63, lr = l & 15, lg = l >> 4;
    const int wr = w >> 1, wc = w & 1;
    const int sr = tid >> 2, seg = tid & 3;

    for (int kt = 0; kt < 16; ++kt) {
        int k0 = kt * 32;
        __syncthreads();
        {
            const float* ap = X + (size_t)(row0 + sr) * DM_ + k0 + seg * 8;
            float4 a0 = *(const float4*)ap;
            float4 a1 = *(const float4*)(ap + 4);
            short8 av;
            av[0] = (short)f2bf(a0.x); av[1] = (short)f2bf(a0.y);
            av[2] = (short)f2bf(a0.z); av[3] = (short)f2bf(a0.w);
            av[4] = (short)f2bf(a1.x); av[5] = (short)f2bf(a1.y);
            av[6] = (short)f2bf(a1.z); av[7] = (short)f2bf(a1.w);
            *(short8*)(ldsA + sr * 40 + seg * 8) = av;

            const float* bp = W + (size_t)(col0 + sr) * DM_ + k0 + seg * 8;
            float4 b0 = *(const float4*)bp;
            float4 b1 = *(const float4*)(bp + 4);
            short8 bv;
            bv[0] = (short)f2bf(b0.x); bv[1] = (short)f2bf(b0.y);
            bv[2] = (short)f2bf(b0.z); bv[3] = (short)f2bf(b0.w);
            bv[4] = (short)f2bf(b1.x); bv[5] = (short)f2bf(b1.y);
            bv[6] = (short)f2bf(b1.z); bv[7] = (short)f2bf(b1.w);
            *(short8*)(ldsB + sr * 40 + seg * 8) = bv;
        }
        __syncthreads();
        short8 af0 = *(short8*)(ldsA + (32 * wr + lr) * 40 + lg * 8);
        short8 af1 = *(short8*)(ldsA + (32 * wr + 16 + lr) * 40 + lg * 8);
        short8 bf0 = *(short8*)(ldsB + (32 * wc + lr) * 40 + lg * 8);
        short8 bf1 = *(short8*)(ldsB + (32 * wc + 16 + lr) * 40 + lg * 8);
        acc[0][0] = __builtin_amdgcn_mfma_f32_16x16x32_bf16(af0, bf0, acc[0][0], 0, 0, 0);
        acc[0][1] = __builtin_amdgcn_mfma_f32_16x16x32_bf16(af0, bf1, acc[0][1], 0, 0, 0);
        acc[1][0] = __builtin_amdgcn_mfma_f32_16x16x32_bf16(af1, bf0, acc[1][0], 0, 0, 0);
        acc[1][1] = __builtin_amdgcn_mfma_f32_16x16x32_bf16(af1, bf1, acc[1][1], 0, 0, 0);
    }
}

// ---------------------------------------------------------------------------
// K1: projections. mode: 0=q (qu=q+u_bias, qv=q+v_bias), 1=k, 2=v (transposed), 3=pe
// ---------------------------------------------------------------------------
__global__ __launch_bounds__(256) void proj_kernel(
    const float* __restrict__ q_in, const float* __restrict__ k_in,
    const float* __restrict__ v_in, const float* __restrict__ p_in,
    const float* __restrict__ Wq, const float* __restrict__ Wk,
    const float* __restrict__ Wv, const float* __restrict__ Wp,
    const float* __restrict__ bq, const float* __restrict__ bk,
    const float* __restrict__ bv,
    const float* __restrict__ ub, const float* __restrict__ vb,
    unsigned short* __restrict__ quB, unsigned short* __restrict__ qvB,
    unsigned short* __restrict__ kB, unsigned short* __restrict__ peB,
    unsigned short* __restrict__ vtB) {
    __shared__ unsigned short ldsA[64 * 40];
    __shared__ unsigned short ldsB[64 * 40];

    const int mode = blockIdx.z;
    const float* X = (mode == 0) ? q_in : (mode == 1) ? k_in : (mode == 2) ? v_in : p_in;
    const float* W = (mode == 0) ? Wq : (mode == 1) ? Wk : (mode == 2) ? Wv : Wp;
    const float* bias = (mode == 0) ? bq : (mode == 1) ? bk : (mode == 2) ? bv : nullptr;

    const int row0 = blockIdx.x * 64, col0 = blockIdx.y * 64;
    f32x4 acc[2][2];
    for (int i = 0; i < 2; ++i)
        for (int j = 0; j < 2; ++j)
            acc[i][j] = (f32x4){0.f, 0.f, 0.f, 0.f};

    gemm64_tile(X, W, row0, col0, ldsA, ldsB, acc);

    const int tid = threadIdx.x;
    const int w = tid >> 6, l = tid & 63, lr = l & 15, lg = l >> 4;
    const int wr = w >> 1, wc = w & 1;

    for (int i = 0; i < 2; ++i) {
        for (int j = 0; j < 2; ++j) {
            int colg = col0 + 32 * wc + 16 * j + lr;
            int h = colg >> 5, d = colg & 31;
            float bb = bias ? bias[colg] : 0.f;
            int rbase = row0 + 32 * wr + 16 * i + 4 * lg;
            if (mode == 2) {
                int b = rbase >> 11;
                int s0 = rbase & 2047;
                ushort4 pk;
                pk.x = f2bf(acc[i][j][0] + bb);
                pk.y = f2bf(acc[i][j][1] + bb);
                pk.z = f2bf(acc[i][j][2] + bb);
                pk.w = f2bf(acc[i][j][3] + bb);
                size_t o = ((size_t)((b * H_ + h) * D_ + d)) * S_ + s0;
                *(ushort4*)(vtB + o) = pk;
            } else {
                float ubv = 0.f, vbv = 0.f;
                if (mode == 0) { ubv = ub[colg]; vbv = vb[colg]; }
                for (int e = 0; e < 4; ++e) {
                    int rg = rbase + e;
                    int b = rg >> 11, s = rg & 2047;
                    size_t o = ((size_t)((b * H_ + h) * S_ + s)) * D_ + d;
                    float y = acc[i][j][e] + bb;
                    if (mode == 0) {
                        quB[o] = f2bf(y + ubv);
                        qvB[o] = f2bf(y + vbv);
                    } else if (mode == 1) {
                        kB[o] = f2bf(y);
                    } else {
                        peB[o] = f2bf(y);
                    }
                }
            }
        }
    }
}

// ---------------------------------------------------------------------------
// K2: fused content+pos scores, softmax, attn write (fp32), PV -> ctx
// grid (S/16, H, B), 512 threads = 8 waves, ~74 KB LDS -> 2 blocks/CU
// ---------------------------------------------------------------------------
__global__ __launch_bounds__(512) void attn_kernel(
    const unsigned short* __restrict__ quB, const unsigned short* __restrict__ qvB,
    const unsigned short* __restrict__ kB, const unsigned short* __restrict__ peB,
    const unsigned short* __restrict__ vtB, const unsigned char* __restrict__ mask,
    float* __restrict__ attn_out, float* __restrict__ ctx) {
    __shared__ unsigned short sc[16 * SCW];  // bf16 scores -> bf16 exp(s-m)
    __shared__ float red[4 * 16 * 33];       // PV wave partials (padded stride 33)
    __shared__ float rowm[16], rowl[16];

    const int tid = threadIdx.x, w = tid >> 6, l = tid & 63, lr = l & 15, lg = l >> 4;
    const int q0 = blockIdx.x * 16, h = blockIdx.y, b = blockIdx.z;
    const size_t headoff = ((size_t)(b * H_ + h)) * S_ * D_;
    const float SCALE = 0.044194173824159216f;

    // A-fragments (held in registers for the whole kernel)
    short8 qu_f = *(const short8*)(quB + headoff + (size_t)(q0 + lr) * D_ + lg * 8);
    short8 qvA_f = *(const short8*)(qvB + headoff + (size_t)(q0 + lr) * D_ + lg * 8);
    int rB = q0 + 1 + lr; if (rB > S_ - 1) rB = S_ - 1;
    short8 qvB_f = *(const short8*)(qvB + headoff + (size_t)rB * D_ + lg * 8);

    // ---- content pass (barrier-free; waves own disjoint 16-col tiles) ----
    for (int j = w; j < 128; j += 8) {
        int c0 = 16 * j;
        short8 bfr = *(const short8*)(kB + headoff + (size_t)(c0 + lr) * D_ + lg * 8);
        f32x4 dd = (f32x4){0.f, 0.f, 0.f, 0.f};
        dd = __builtin_amdgcn_mfma_f32_16x16x32_bf16(qu_f, bfr, dd, 0, 0, 0);
        float mk = mask[b * S_ + c0 + lr] ? -1e9f : 0.f;
        for (int i = 0; i < 4; ++i) {
            sc[(4 * lg + i) * SCW + c0 + lr] = f2bf(dd[i] * SCALE + mk);
        }
    }
    __syncthreads();

    // ---- pos pass A: delta = k'-q in [-q, 0]; uses P[q][S-1+delta] ----
    {
        int ntA = q0 / 16 + 1;
        for (int ju = w; ju < ntA; ju += 8) {
            int u = 16 * ju + lr;
            int pr = S_ - 16 - q0 + u; if (pr > S_ - 1) pr = S_ - 1;
            short8 pf = *(const short8*)(peB + headoff + (size_t)pr * D_ + lg * 8);
            f32x4 dd = (f32x4){0.f, 0.f, 0.f, 0.f};
            dd = __builtin_amdgcn_mfma_f32_16x16x32_bf16(qvA_f, pf, dd, 0, 0, 0);
            int delta = u - (q0 + 15);
            for (int i = 0; i < 4; ++i) {
                int r = 4 * lg + i, q = q0 + r;
                if (delta <= 0 && delta >= -q) {
                    int a = r * SCW + q + delta;
                    sc[a] = f2bf(bf2f(sc[a]) + dd[i] * SCALE);
                }
            }
        }
    }
    // ---- pos pass B: delta = k'-q in [2, S-1-q]; uses P[q+1][delta-2] ----
    {
        int ntB = (S_ - q0) / 16;
        for (int ju = w; ju < ntB; ju += 8) {
            int u = 16 * ju + lr;
            int pr = u - 2; if (pr < 0) pr = 0;
            short8 pf = *(const short8*)(peB + headoff + (size_t)pr * D_ + lg * 8);
            f32x4 dd = (f32x4){0.f, 0.f, 0.f, 0.f};
            dd = __builtin_amdgcn_mfma_f32_16x16x32_bf16(qvB_f, pf, dd, 0, 0, 0);
            for (int i = 0; i < 4; ++i) {
                int r = 4 * lg + i, q = q0 + r;
                if (u >= 2 && u <= S_ - 1 - q) {
                    int a = r * SCW + q + u;
                    sc[a] = f2bf(bf2f(sc[a]) + dd[i] * SCALE);
                }
            }
        }
    }
    __syncthreads();

    const int r = tid >> 5, ci = tid & 31;
    // ---- S1: row max (vectorized, conflict-free consecutive chunks) ----
    {
        const unsigned short* rp = sc + r * SCW;
        float m = -1e30f;
        for (int k2 = 0; k2 < 8; ++k2) {
            short8 vv = *(const short8*)(rp + ci * 8 + k2 * 256);
            for (int jj = 0; jj < 8; ++jj) m = fmaxf(m, bf2f(vv[jj]));
        }
        for (int off = 1; off < 32; off <<= 1) m = fmaxf(m, __shfl_xor(m, off));
        if (ci == 0) rowm[r] = m;
    }
    __syncthreads();

    // ---- S2: single exp pass; store bf16 exp(s-m) back; row sum ----
    {
        unsigned short* rp = sc + r * SCW;
        float m = rowm[r];
        float sum = 0.f;
        for (int k2 = 0; k2 < 8; ++k2) {
            short8 vv = *(short8*)(rp + ci * 8 + k2 * 256);
            short8 ee;
            for (int jj = 0; jj < 8; ++jj) {
                float e = __expf(bf2f(vv[jj]) - m);
                sum += e;
                ee[jj] = (short)f2bf(e);
            }
            *(short8*)(rp + ci * 8 + k2 * 256) = ee;
        }
        for (int off = 1; off < 32; off <<= 1) sum += __shfl_xor(sum, off);
        if (ci == 0) rowl[r] = sum;
    }
    __syncthreads();

    // ---- S3 (waves 4-7: HBM attn write) || PV (waves 0-3: MFMA) ----
    if (w >= 4) {
        int tt = tid - 256;
        float* abase = attn_out + ((size_t)((b * H_ + h) * S_ + q0)) * S_;
        for (int idx = tt; idx < 16 * 512; idx += 256) {
            int r2 = idx >> 9, c4 = idx & 511;
            float li = 1.0f / rowl[r2];
            ushort4 s4 = *(ushort4*)(sc + r2 * SCW + c4 * 4);
            float4 av;
            av.x = bf2f(s4.x) * li;
            av.y = bf2f(s4.y) * li;
            av.z = bf2f(s4.z) * li;
            av.w = bf2f(s4.w) * li;
            *(float4*)(abase + (size_t)r2 * S_ + c4 * 4) = av;
        }
    } else {
        f32x4 a0 = (f32x4){0.f, 0.f, 0.f, 0.f};
        f32x4 a1 = (f32x4){0.f, 0.f, 0.f, 0.f};
        const unsigned short* vbase = vtB + ((size_t)(b * H_ + h)) * D_ * S_;
        for (int ks = 0; ks < 16; ++ks) {
            int koff = 512 * w + 32 * ks;
            short8 af = *(short8*)(sc + lr * SCW + koff + lg * 8);
            short8 b0 = *(const short8*)(vbase + (size_t)lr * S_ + koff + lg * 8);
            short8 b1 = *(const short8*)(vbase + (size_t)(16 + lr) * S_ + koff + lg * 8);
            a0 = __builtin_amdgcn_mfma_f32_16x16x32_bf16(af, b0, a0, 0, 0, 0);
            a1 = __builtin_amdgcn_mfma_f32_16x16x32_bf16(af, b1, a1, 0, 0, 0);
        }
        for (int i = 0; i < 4; ++i) {
            red[(w * 16 + 4 * lg + i) * 33 + lr] = a0[i];
            red[(w * 16 + 4 * lg + i) * 33 + 16 + lr] = a1[i];
        }
    }
    __syncthreads();

    // ---- final: reduce PV partials, scale by 1/l, write ctx ----
    {
        int r2 = tid >> 5, d = tid & 31;
        float s = red[(r2) * 33 + d] + red[(16 + r2) * 33 + d] +
                  red[(32 + r2) * 33 + d] + red[(48 + r2) * 33 + d];
        float li = 1.0f / rowl[r2];
        ctx[((size_t)(b * S_ + q0 + r2)) * DM_ + h * D_ + d] = s * li;
    }
}

// ---------------------------------------------------------------------------
// K3: out = ctx @ Wo^T + bo
// ---------------------------------------------------------------------------
__global__ __launch_bounds__(256) void outproj_kernel(
    const float* __restrict__ ctx, const float* __restrict__ Wo,
    const float* __restrict__ bo, float* __restrict__ outp) {
    __shared__ unsigned short ldsA[64 * 40];
    __shared__ unsigned short ldsB[64 * 40];
    const int row0 = blockIdx.x * 64, col0 = blockIdx.y * 64;
    f32x4 acc[2][2];
    for (int i = 0; i < 2; ++i)
        for (int j = 0; j < 2; ++j)
            acc[i][j] = (f32x4){0.f, 0.f, 0.f, 0.f};
    gemm64_tile(ctx, Wo, row0, col0, ldsA, ldsB, acc);
    const int tid = threadIdx.x;
    const int w = tid >> 6, l = tid & 63, lr = l & 15, lg = l >> 4;
    const int wr = w >> 1, wc = w & 1;
    for (int i = 0; i < 2; ++i) {
        for (int j = 0; j < 2; ++j) {
            int colg = col0 + 32 * wc + 16 * j + lr;
            float bb = bo[colg];
            int rbase = row0 + 32 * wr + 16 * i + 4 * lg;
            for (int e = 0; e < 4; ++e) {
                outp[(size_t)(rbase + e) * DM_ + colg] = acc[i][j][e] + bb;
            }
        }
    }
}

extern "C" void kernel_launch(void* const* d_in, const int* in_sizes, int n_in,
                              void* d_out, int out_size, void* d_ws, size_t ws_size,
                              hipStream_t stream) {
    const float* q_in = (const float*)d_in[0];
    const float* k_in = (const float*)d_in[1];
    const float* v_in = (const float*)d_in[2];
    const float* p_in = (const float*)d_in[3];
    const unsigned char* mask = (const unsigned char*)d_in[4];
    const float* Wq = (const float*)d_in[5];
    const float* bq = (const float*)d_in[6];
    const float* Wk = (const float*)d_in[7];
    const float* bk = (const float*)d_in[8];
    const float* Wv = (const float*)d_in[9];
    const float* bv = (const float*)d_in[10];
    const float* Wp = (const float*)d_in[11];
    const float* ub = (const float*)d_in[12];
    const float* vb = (const float*)d_in[13];
    const float* Wo = (const float*)d_in[14];
    const float* bo = (const float*)d_in[15];

    char* ws = (char*)d_ws;
    const size_t BUF = 1u << 22;  // 4 MB per bf16 [B,H,S,D] buffer
    unsigned short* quB = (unsigned short*)(ws);
    unsigned short* qvB = (unsigned short*)(ws + BUF);
    unsigned short* kB  = (unsigned short*)(ws + 2 * BUF);
    unsigned short* peB = (unsigned short*)(ws + 3 * BUF);
    unsigned short* vtB = (unsigned short*)(ws + 4 * BUF);
    float* ctx = (float*)(ws + 5 * BUF);  // [B*S][512] fp32, 8 MB

    float* outp = (float*)d_out;
    float* attn = outp + (size_t)B_ * S_ * DM_;

    hipLaunchKernelGGL(proj_kernel, dim3(64, 8, 4), dim3(256), 0, stream,
                       q_in, k_in, v_in, p_in, Wq, Wk, Wv, Wp, bq, bk, bv,
                       ub, vb, quB, qvB, kB, peB, vtB);
    hipLaunchKernelGGL(attn_kernel, dim3(S_ / 16, H_, B_), dim3(512), 0, stream,
                       quB, qvB, kB, peB, vtB, mask, attn, ctx);
    hipLaunchKernelGGL(outproj_kernel, dim3(64, 8, 1), dim3(256), 0, stream,
                       ctx, Wo, bo, outp);
}